// Round 7
// baseline (83.475 us; speedup 1.0000x reference)
//
#include <hip/hip_runtime.h>
#include <hip/hip_bf16.h>

// Problem constants (from setup_inputs): price_data float32 [64, 4096, 64]
#define B 64
#define S 4096
#define C 64
#define NCHUNK 16            // s-chunks per batch in K1; block = (b, chunk)
#define LCH (S / NCHUNK)     // 256 s per K1 block
#define SPT (LCH / 16)       // 16 s per thread-slice (16 slices per block)

// native clang vector type (usable with __builtin_nontemporal_store)
typedef float f32x4 __attribute__((ext_vector_type(4)));

// Partials in ws: part[p][ (b*NCHUNK + chunk)*64 + c ], p: 0=sum 1=sumsq
// 2=gain 3=loss 4=sum12 5=sum26
#define PSTRIDE ((size_t)B * NCHUNK * 64)   // 65536 floats per plane (1.5 MB total)

__device__ inline f32x4 vmax0(f32x4 a) {
    f32x4 r;
    r.x = fmaxf(a.x, 0.f);
    r.y = fmaxf(a.y, 0.f);
    r.z = fmaxf(a.z, 0.f);
    r.w = fmaxf(a.w, 0.f);
    return r;
}

// K1: pure partial reduction (no output writes). 1024 blocks x 256 threads.
// tid = slice*16 + c4; 16B/lane loads, fully coalesced.
__global__ __launch_bounds__(256) void ti_reduce(const f32x4* __restrict__ in4,
                                                 float* __restrict__ part) {
    const int b     = blockIdx.x / NCHUNK;
    const int chunk = blockIdx.x % NCHUNK;
    const int tid   = threadIdx.x;
    const int sl    = tid >> 4;     // s-slice 0..15
    const int c4    = tid & 15;     // float4 channel group 0..15
    const int s0    = chunk * LCH + sl * SPT;

    const size_t rowbase = (size_t)b * S;

    f32x4 acc[6];
    #pragma unroll
    for (int p = 0; p < 6; ++p) acc[p] = (f32x4){0.f, 0.f, 0.f, 0.f};

    f32x4 prev = (f32x4){0.f, 0.f, 0.f, 0.f};
    if (s0 > 0) prev = in4[(rowbase + s0 - 1) * 16 + c4];

    #pragma unroll 8
    for (int j = 0; j < SPT; ++j) {
        const int s = s0 + j;
        const f32x4 v = in4[(rowbase + s) * 16 + c4];
        acc[0] += v;
        acc[1] += v * v;
        if (s > 0) {
            const f32x4 d = v - prev;
            acc[2] += vmax0(d);
            acc[3] += vmax0(-d);
        }
        prev = v;
        if (s >= S - 26) {
            acc[5] += v;
            if (s >= S - 12) acc[4] += v;
        }
    }

    // Cross-slice reduce in LDS: lds[p][sl][ch]
    __shared__ float lds[6][16][64];
    #pragma unroll
    for (int p = 0; p < 6; ++p) *(f32x4*)&lds[p][sl][c4 * 4] = acc[p];
    __syncthreads();

    if (tid < 64) {
        const size_t idx = ((size_t)(b * NCHUNK + chunk)) * 64 + tid;
        #pragma unroll
        for (int p = 0; p < 6; ++p) {
            float t = 0.f;
            #pragma unroll
            for (int s2 = 0; s2 < 16; ++s2) t += lds[p][s2][tid];
            part[(size_t)p * PSTRIDE + idx] = t;
        }
    }
}

// K2: fold partials -> stats (redundantly per block, overlapped) + write FULL
// output rows as one perfectly linear stream. 1024 blocks x 320 threads
// (5 waves); block = (b, 256-row segment). Thread t: row_off=t/80, q=t%80
// (loop-invariant). Each iteration stores 4 complete rows = 5120B contiguous
// per block-span. Copy lanes (q<16) re-read the L3-resident input.
__global__ __launch_bounds__(320) void ti_write(const f32x4* __restrict__ in4,
                                                const float* __restrict__ part,
                                                f32x4* __restrict__ out4) {
    const int blk = blockIdx.x;
    const int b   = blk >> 4;           // 0..63
    const int seg = blk & 15;           // 0..15 (256 rows each)
    const int tid = threadIdx.x;        // 0..319

    __shared__ float sums[6][64];
    __shared__ f32x4 st4[4][16];

    // ---- fold partials for this b: 384 tasks over 320 threads ----
    #pragma unroll
    for (int t = tid; t < 384; t += 320) {
        const int p = t >> 6, c = t & 63;
        float a = 0.f;
        #pragma unroll
        for (int ch = 0; ch < NCHUNK; ++ch)
            a += part[(size_t)p * PSTRIDE + (size_t)(b * NCHUNK + ch) * 64 + c];
        sums[p][c] = a;
    }
    __syncthreads();

    if (tid < 64) {
        const float sum = sums[0][tid], sumsq = sums[1][tid];
        const float gain = sums[2][tid], loss = sums[3][tid];
        const float s12 = sums[4][tid], s26 = sums[5][tid];

        const float inv_sm1 = 1.f / (float)(S - 1);
        const float ag = gain * inv_sm1;
        const float al = loss * inv_sm1;
        const float rs = ag / (al + 1e-7f);
        const float rsi = 100.f - 100.f / (1.f + rs);

        const float macd = s12 * (1.f / 12.f) - s26 * (1.f / 26.f);

        const float sma = sum * (1.f / (float)S);
        const float var = sumsq * (1.f / (float)S) - sma * sma;
        const float sd = sqrtf(fmaxf(var, 0.f));

        float* stf = (float*)st4;   // stf[which*64 + c]
        stf[0 * 64 + tid] = rsi;
        stf[1 * 64 + tid] = macd;
        stf[2 * 64 + tid] = sma + 2.f * sd;
        stf[3 * 64 + tid] = sma - 2.f * sd;
    }
    __syncthreads();

    // ---- per-thread invariants ----
    const int row_off = tid / 80;       // 0..3 (one int div, at entry)
    const int q       = tid - row_off * 80;   // 0..79, loop-invariant
    const bool is_copy = (q < 16);
    f32x4 bval;
    if (!is_copy) bval = st4[(q >> 4) - 1][q & 15];

    const size_t base_row = (size_t)b * S + (size_t)seg * 256 + row_off;

    // 64 iterations x 4 rows = 256 rows; stores are a linear 320MB stream.
    #pragma unroll 4
    for (int it = 0; it < 64; ++it) {
        const size_t row = base_row + (size_t)it * 4;
        f32x4 v = bval;
        if (is_copy) v = in4[row * 16 + q];
        __builtin_nontemporal_store(v, &out4[row * 80 + q]);
    }
}

extern "C" void kernel_launch(void* const* d_in, const int* in_sizes, int n_in,
                              void* d_out, int out_size, void* d_ws, size_t ws_size,
                              hipStream_t stream) {
    const f32x4* in4 = (const f32x4*)d_in[0];
    f32x4* out4 = (f32x4*)d_out;
    float* part = (float*)d_ws;            // 6 * 65536 floats = 1.5 MB

    ti_reduce<<<B * NCHUNK, 256, 0, stream>>>(in4, part);
    ti_write<<<B * 16, 320, 0, stream>>>(in4, part, out4);
}